// Round 1
// baseline (765.893 us; speedup 1.0000x reference)
//
#include <hip/hip_runtime.h>
#include <cfloat>
#include <cstdint>

// KNN classify: X[1024,128] f32, X_train[100000,128] f32, y_train[100000] i32, k=5.
// Rank by s = ||t||^2 - 2*x.t  (equivalent ordering to reference's sqrt(clamp(
// ||x||^2+||t||^2-2 x.t))); ties broken by smaller train index (lax.top_k stable).
// Vote: count labels among top-5, argmax with smallest-class tie-break.

#define T 1024
#define D 128
#define NTRAIN 100000
#define MT 64           // tests per block
#define NT 64           // trains per tile
#define CHUNK 3200      // trains per block (grid.y chunk)
#define NCHUNK 32       // 32*3200 = 102400 >= 100000
#define TILES_PER_CHUNK 50
#define LDAP 132        // padded LDS row stride in floats (132*4B = 528B, 16B aligned)
#define KNN 5
#define NUM_CLASSES 10

struct Cand { float s; int j; };

__device__ __forceinline__ bool better(float s, int j, const Cand& c) {
    return (s < c.s) || (s == c.s && j < c.j);
}

// static-index insertion into sorted-5 list (no dynamic register indexing -> no scratch)
__device__ __forceinline__ void ins5(Cand t5[KNN], float s, int j) {
    if (!better(s, j, t5[4])) return;
    if (better(s, j, t5[0]))      { t5[4]=t5[3]; t5[3]=t5[2]; t5[2]=t5[1]; t5[1]=t5[0]; t5[0]={s,j}; }
    else if (better(s, j, t5[1])) { t5[4]=t5[3]; t5[3]=t5[2]; t5[2]=t5[1]; t5[1]={s,j}; }
    else if (better(s, j, t5[2])) { t5[4]=t5[3]; t5[3]=t5[2]; t5[2]={s,j}; }
    else if (better(s, j, t5[3])) { t5[4]=t5[3]; t5[3]={s,j}; }
    else                          { t5[4]={s,j}; }
}

__global__ __launch_bounds__(256, 2)
void knn_partial(const float* __restrict__ X, const float* __restrict__ XT,
                 Cand* __restrict__ part) {
    // LDS: A tile (64x132 f32 = 33.8KB) + B tile (64x132 = 33.8KB); cand merge
    // buffer (64*16*5*8B = 40KB) reuses the same space after the tile loop.
    __shared__ __align__(16) char smem[(MT + NT) * LDAP * 4];
    __shared__ float nrm[NT];
    float* As = (float*)smem;
    float* Bs = As + MT * LDAP;
    Cand* cand = (Cand*)smem;

    const int tid = threadIdx.x;
    const int bx  = blockIdx.x;   // test tile 0..15
    const int bc  = blockIdx.y;   // chunk 0..31
    const int tm  = tid >> 4;     // 0..15 -> tests tm*4..tm*4+3
    const int tn  = tid & 15;     // 0..15 -> trains {tn, tn+16, tn+32, tn+48}

    // ---- stage A (test rows bx*64 .. +63), fully in range ----
    {
        const int r0 = tid >> 5;            // 0..7
        const int c4 = (tid & 31) << 2;     // float col 0..124 step 4
#pragma unroll
        for (int p = 0; p < 8; ++p) {
            const int r = p * 8 + r0;
            float4 v = *(const float4*)&X[(bx * MT + r) * D + c4];
            *(float4*)&As[r * LDAP + c4] = v;
        }
    }

    Cand top[4][KNN];
#pragma unroll
    for (int i = 0; i < 4; ++i)
#pragma unroll
        for (int e = 0; e < KNN; ++e) top[i][e] = {FLT_MAX, 0x7fffffff};

    const int jbase0 = bc * CHUNK;

    for (int t = 0; t < TILES_PER_CHUNK; ++t) {
        const int jb = jbase0 + t * NT;
        __syncthreads();
        // ---- stage B tile + per-row squared norms (shfl reduce over 32 lanes) ----
        {
            const int r0 = tid >> 5;
            const int c4 = (tid & 31) << 2;
#pragma unroll
            for (int p = 0; p < 8; ++p) {
                const int r = p * 8 + r0;
                const int j = jb + r;
                float4 v = make_float4(0.f, 0.f, 0.f, 0.f);
                if (j < NTRAIN) v = *(const float4*)&XT[j * D + c4];
                *(float4*)&Bs[r * LDAP + c4] = v;
                float pn = v.x * v.x + v.y * v.y + v.z * v.z + v.w * v.w;
                pn += __shfl_xor(pn, 1);
                pn += __shfl_xor(pn, 2);
                pn += __shfl_xor(pn, 4);
                pn += __shfl_xor(pn, 8);
                pn += __shfl_xor(pn, 16);
                if ((tid & 31) == 0) nrm[r] = pn;
            }
        }
        __syncthreads();

        // ---- 4x4 micro-tile dot products over full K=128 ----
        float acc[4][4];
#pragma unroll
        for (int i = 0; i < 4; ++i)
#pragma unroll
            for (int jj = 0; jj < 4; ++jj) acc[i][jj] = 0.f;

#pragma unroll 2
        for (int k4 = 0; k4 < 32; ++k4) {
            float4 a[4], b[4];
#pragma unroll
            for (int i = 0; i < 4; ++i)
                a[i] = *(const float4*)&As[(tm * 4 + i) * LDAP + k4 * 4];
#pragma unroll
            for (int jj = 0; jj < 4; ++jj)
                b[jj] = *(const float4*)&Bs[(tn + 16 * jj) * LDAP + k4 * 4];
#pragma unroll
            for (int i = 0; i < 4; ++i)
#pragma unroll
                for (int jj = 0; jj < 4; ++jj) {
                    acc[i][jj] = fmaf(a[i].x, b[jj].x, acc[i][jj]);
                    acc[i][jj] = fmaf(a[i].y, b[jj].y, acc[i][jj]);
                    acc[i][jj] = fmaf(a[i].z, b[jj].z, acc[i][jj]);
                    acc[i][jj] = fmaf(a[i].w, b[jj].w, acc[i][jj]);
                }
        }

        // ---- score + running top-5 insert ----
#pragma unroll
        for (int jj = 0; jj < 4; ++jj) {
            const int j = jb + tn + 16 * jj;
            if (j < NTRAIN) {
                const float nj = nrm[tn + 16 * jj];
#pragma unroll
                for (int i = 0; i < 4; ++i) {
                    const float s = fmaf(-2.f, acc[i][jj], nj);
                    ins5(top[i], s, j);
                }
            }
        }
    }

    // ---- block merge: 16 contributors per test row -> block top-5 ----
    __syncthreads();   // done with As/Bs; reuse as cand buffer
#pragma unroll
    for (int i = 0; i < 4; ++i)
#pragma unroll
        for (int e = 0; e < KNN; ++e)
            cand[((tm * 4 + i) * 16 + tn) * KNN + e] = top[i][e];
    __syncthreads();

    if (tid < MT) {
        Cand best[KNN];
#pragma unroll
        for (int e = 0; e < KNN; ++e) best[e] = {FLT_MAX, 0x7fffffff};
        for (int c = 0; c < 16; ++c)
#pragma unroll
            for (int e = 0; e < KNN; ++e) {
                const Cand cc = cand[(tid * 16 + c) * KNN + e];
                ins5(best, cc.s, cc.j);
            }
        const int gi = bx * MT + tid;
#pragma unroll
        for (int e = 0; e < KNN; ++e)
            part[(gi * NCHUNK + bc) * KNN + e] = best[e];
    }
}

__global__ void knn_vote(const Cand* __restrict__ part, const int* __restrict__ y,
                         float* __restrict__ out) {
    const int i = blockIdx.x * blockDim.x + threadIdx.x;
    if (i >= T) return;
    Cand best[KNN];
#pragma unroll
    for (int e = 0; e < KNN; ++e) best[e] = {FLT_MAX, 0x7fffffff};
    for (int c = 0; c < NCHUNK; ++c)
#pragma unroll
        for (int e = 0; e < KNN; ++e) {
            const Cand cc = part[(i * NCHUNK + c) * KNN + e];
            ins5(best, cc.s, cc.j);
        }
    int lbl[KNN];
#pragma unroll
    for (int e = 0; e < KNN; ++e) lbl[e] = y[best[e].j];

    int bestc = 0, bestcnt = -1;
#pragma unroll
    for (int c = 0; c < NUM_CLASSES; ++c) {
        int cnt = 0;
#pragma unroll
        for (int e = 0; e < KNN; ++e) cnt += (lbl[e] == c) ? 1 : 0;
        if (cnt > bestcnt) { bestcnt = cnt; bestc = c; }  // strict > keeps smallest class on ties
    }
    out[i] = (float)bestc;
}

extern "C" void kernel_launch(void* const* d_in, const int* in_sizes, int n_in,
                              void* d_out, int out_size, void* d_ws, size_t ws_size,
                              hipStream_t stream) {
    const float* X  = (const float*)d_in[0];
    const float* XT = (const float*)d_in[1];
    const int*   y  = (const int*)d_in[2];
    // d_in[3] = k (always 5 in this problem; KNN hardcoded)

    Cand* part = (Cand*)d_ws;   // 1024 * 32 * 5 * 8B = 1.31 MB partial top-5s

    knn_partial<<<dim3(16, NCHUNK), 256, 0, stream>>>(X, XT, part);
    knn_vote<<<dim3((T + 255) / 256), 256, 0, stream>>>(part, y, (float*)d_out);
}

// Round 2
// 596.571 us; speedup vs baseline: 1.2838x; 1.2838x over previous
//
#include <hip/hip_runtime.h>
#include <cfloat>
#include <cstdint>

// KNN classify via split-f16 MFMA emulated-fp32 GEMM.
// key = dot(x,t) - ||t||^2/2  (monotone in -distance; test norm constant per row).
// dot computed as hiA*hiB + hiA*loB + loA*hiB in f32-accum MFMA; -nrm/2 folded in
// as an augmented K column (A_ext = -nrm/2 split hi/lo, B_ext = 1.0).
// Top-5 largest keys, ties -> smaller train index (matches lax.top_k on -dist).

#define NTRAIN 100000
#define D 128
#define T 1024
#define TB 256        // tests per block (4 waves x 64)
#define NT 32         // trains per tile
#define CPAD 152      // LDS row stride in f16: 128 data + 1 nrm + 15 zero + 8 pad
#define KNN 5
#define NUM_CLASSES 10
#define DEF_NCH 125   // 125 chunks x 800 trains = 100000 exactly

typedef _Float16 half8 __attribute__((ext_vector_type(8)));
typedef _Float16 half4 __attribute__((ext_vector_type(4)));
typedef float f32x16 __attribute__((ext_vector_type(16)));

#define MFMA(a, b, c) __builtin_amdgcn_mfma_f32_32x32x16_f16((a), (b), (c), 0, 0, 0)

struct Cand { float s; int j; };

__device__ __forceinline__ bool better(float s, int j, const Cand& c) {
    return (s > c.s) || (s == c.s && j < c.j);   // larger key = nearer; tie -> smaller idx
}

// static-index insertion into sorted-5 (best first); no dynamic reg indexing
__device__ __forceinline__ void ins5(Cand t5[KNN], float s, int j) {
    if (!better(s, j, t5[4])) return;
    if (better(s, j, t5[0]))      { t5[4]=t5[3]; t5[3]=t5[2]; t5[2]=t5[1]; t5[1]=t5[0]; t5[0]={s,j}; }
    else if (better(s, j, t5[1])) { t5[4]=t5[3]; t5[3]=t5[2]; t5[2]=t5[1]; t5[1]={s,j}; }
    else if (better(s, j, t5[2])) { t5[4]=t5[3]; t5[3]=t5[2]; t5[2]={s,j}; }
    else if (better(s, j, t5[3])) { t5[4]=t5[3]; t5[3]={s,j}; }
    else                          { t5[4]={s,j}; }
}

__global__ __launch_bounds__(256, 2)
void knn_mfma(const float* __restrict__ X, const float* __restrict__ XT,
              Cand* __restrict__ part, int nch, int chunk) {
    __shared__ __align__(16) _Float16 Ah[2][NT][CPAD];
    __shared__ __align__(16) _Float16 Al[2][NT][CPAD];

    const int tid  = threadIdx.x;
    const int lane = tid & 63;
    const int wm   = tid >> 6;            // wave id = test group (0..3)
    const int bx   = blockIdx.x;          // test block (0..3)
    const int bc   = blockIdx.y;          // train chunk

    // ---- one-time zero of augment cols 128..151 (both bufs, both arrays) ----
    if (tid < 128) {
        const int buf = tid >> 6, arr = (tid >> 5) & 1, row = tid & 31;
        _Float16* p = arr ? &Al[buf][row][0] : &Ah[buf][row][0];
#pragma unroll
        for (int cc = 128; cc < 152; ++cc) p[cc] = (_Float16)0.0f;
    }

    // ---- persistent B (tests) fragments in registers: 2 colfrags x 8 ksteps, hi/lo ----
    half8 Bh[2][8], Bl[2][8];
#pragma unroll
    for (int c = 0; c < 2; ++c) {
        const int trow = bx * TB + wm * 64 + c * 32 + (lane & 31);
        const float* xp = &X[(size_t)trow * D + (lane >> 5) * 8];
#pragma unroll
        for (int ks = 0; ks < 8; ++ks) {
            float4 v0 = *(const float4*)&xp[ks * 16];
            float4 v1 = *(const float4*)&xp[ks * 16 + 4];
            float a[8] = {v0.x, v0.y, v0.z, v0.w, v1.x, v1.y, v1.z, v1.w};
#pragma unroll
            for (int e = 0; e < 8; ++e) {
                _Float16 hh = (_Float16)a[e];
                Bh[c][ks][e] = hh;
                Bl[c][ks][e] = (_Float16)(a[e] - (float)hh);
            }
        }
    }
    // augment B fragment: k=128 element is 1.0 (held by lanes<32, elem 0), rest 0
    half8 B8;
#pragma unroll
    for (int e = 0; e < 8; ++e) B8[e] = (_Float16)0.0f;
    if (lane < 32) B8[0] = (_Float16)1.0f;

    // ---- staging helpers (T14 split: issue loads early, convert+write late) ----
    const int srow = tid >> 5;            // 0..7
    const int scol = (tid & 31) * 4;      // f32 col
    float4 ld[4];

    auto issue_loads = [&](int jb) {
#pragma unroll
        for (int p = 0; p < 4; ++p) {
            const int j = jb + p * 8 + srow;
            if (j < NTRAIN) ld[p] = *(const float4*)&XT[(size_t)j * D + scol];
            else            ld[p] = make_float4(0.f, 0.f, 0.f, 0.f);
        }
    };
    auto write_stage = [&](int buf) {
#pragma unroll
        for (int p = 0; p < 4; ++p) {
            const int row = p * 8 + srow;
            float4 v = ld[p];
            _Float16 h0 = (_Float16)v.x, h1 = (_Float16)v.y,
                     h2 = (_Float16)v.z, h3 = (_Float16)v.w;
            half4 hv = {h0, h1, h2, h3};
            half4 lv = {(_Float16)(v.x - (float)h0), (_Float16)(v.y - (float)h1),
                        (_Float16)(v.z - (float)h2), (_Float16)(v.w - (float)h3)};
            *(half4*)&Ah[buf][row][scol] = hv;
            *(half4*)&Al[buf][row][scol] = lv;
            float pn = v.x * v.x + v.y * v.y + v.z * v.z + v.w * v.w;
            pn += __shfl_xor(pn, 1);
            pn += __shfl_xor(pn, 2);
            pn += __shfl_xor(pn, 4);
            pn += __shfl_xor(pn, 8);
            pn += __shfl_xor(pn, 16);
            if ((lane & 31) == 0) {
                const float m = -0.5f * pn;
                const _Float16 mh = (_Float16)m;
                Ah[buf][row][128] = mh;
                Al[buf][row][128] = (_Float16)(m - (float)mh);
            }
        }
    };

    Cand top[2][KNN];
#pragma unroll
    for (int c = 0; c < 2; ++c)
#pragma unroll
        for (int e = 0; e < KNN; ++e) top[c][e] = {-FLT_MAX, 0x7fffffff};

    const int arow = lane & 31;
    const int kh   = (lane >> 5) * 8;
    const int jc0  = bc * chunk;
    const int ntiles = chunk >> 5;

    issue_loads(jc0);
    __syncthreads();          // zero-init visible
    write_stage(0);
    __syncthreads();          // tile 0 staged

    for (int t = 0; t < ntiles; ++t) {
        const int jb = jc0 + t * NT;
        if (jb >= NTRAIN) break;                 // uniform across block
        const int buf = t & 1;
        const bool more = (t + 1 < ntiles);
        if (more) issue_loads(jc0 + (t + 1) * NT);

        f32x16 accA, accB;
#pragma unroll
        for (int e = 0; e < 16; ++e) { accA[e] = 0.f; accB[e] = 0.f; }

#pragma unroll
        for (int ks = 0; ks < 8; ++ks) {
            half8 ah = *(half8*)&Ah[buf][arow][ks * 16 + kh];
            half8 al = *(half8*)&Al[buf][arow][ks * 16 + kh];
            accA = MFMA(ah, Bh[0][ks], accA);
            accB = MFMA(ah, Bh[1][ks], accB);
            accA = MFMA(ah, Bl[0][ks], accA);
            accB = MFMA(ah, Bl[1][ks], accB);
            accA = MFMA(al, Bh[0][ks], accA);
            accB = MFMA(al, Bh[1][ks], accB);
        }
        {   // augmented k-step: adds (-nrm/2) via B_ext = 1.0
            half8 ah = *(half8*)&Ah[buf][arow][128 + kh];
            half8 al = *(half8*)&Al[buf][arow][128 + kh];
            accA = MFMA(ah, B8, accA);
            accB = MFMA(ah, B8, accB);
            accA = MFMA(al, B8, accA);
            accB = MFMA(al, B8, accB);
        }

        if (more) write_stage(buf ^ 1);          // vmcnt wait hidden under MFMA phase

        // epilogue: D[train][test] -> col=lane&31 (test), row=(reg&3)+8*(reg>>2)+4*(lane>>5)
        const int rbase = 4 * (lane >> 5);
#pragma unroll
        for (int reg = 0; reg < 16; ++reg) {
            const int row = (reg & 3) + 8 * (reg >> 2) + rbase;
            const int j = jb + row;
            if (j < NTRAIN) {
                ins5(top[0], accA[reg], j);
                ins5(top[1], accB[reg], j);
            }
        }
        __syncthreads();
    }

    // ---- merge lane pairs (l <-> l+32) and write partials ----
#pragma unroll
    for (int c = 0; c < 2; ++c) {
        float os[KNN]; int oj[KNN];
#pragma unroll
        for (int e = 0; e < KNN; ++e) {
            os[e] = __shfl_xor(top[c][e].s, 32);
            oj[e] = __shfl_xor(top[c][e].j, 32);
        }
#pragma unroll
        for (int e = 0; e < KNN; ++e) ins5(top[c], os[e], oj[e]);
        if (lane < 32) {
            const int test = bx * TB + wm * 64 + c * 32 + lane;
            Cand* pp = &part[((size_t)test * nch + bc) * KNN];
#pragma unroll
            for (int e = 0; e < KNN; ++e) pp[e] = top[c][e];
        }
    }
}

__global__ void knn_vote(const Cand* __restrict__ part, const int* __restrict__ y,
                         float* __restrict__ out, int nch) {
    const int i = blockIdx.x * blockDim.x + threadIdx.x;
    if (i >= T) return;
    Cand best[KNN];
#pragma unroll
    for (int e = 0; e < KNN; ++e) best[e] = {-FLT_MAX, 0x7fffffff};
    for (int c = 0; c < nch; ++c) {
#pragma unroll
        for (int e = 0; e < KNN; ++e) {
            const Cand cc = part[((size_t)i * nch + c) * KNN + e];
            if ((unsigned)cc.j < (unsigned)NTRAIN)   // skips init/stale entries
                ins5(best, cc.s, cc.j);
        }
    }
    int lbl[KNN];
#pragma unroll
    for (int e = 0; e < KNN; ++e) lbl[e] = y[best[e].j];

    int bestc = 0, bestcnt = -1;
#pragma unroll
    for (int c = 0; c < NUM_CLASSES; ++c) {
        int cnt = 0;
#pragma unroll
        for (int e = 0; e < KNN; ++e) cnt += (lbl[e] == c) ? 1 : 0;
        if (cnt > bestcnt) { bestcnt = cnt; bestc = c; }  // strict > : smallest class on tie
    }
    out[i] = (float)bestc;
}

extern "C" void kernel_launch(void* const* d_in, const int* in_sizes, int n_in,
                              void* d_out, int out_size, void* d_ws, size_t ws_size,
                              hipStream_t stream) {
    const float* X  = (const float*)d_in[0];
    const float* XT = (const float*)d_in[1];
    const int*   y  = (const int*)d_in[2];
    // d_in[3] = k (always 5; hardcoded)

    int nch = DEF_NCH;
    const size_t per_chunk_bytes = (size_t)T * KNN * sizeof(Cand);  // per chunk across all tests
    if (ws_size > 0 && (size_t)nch * per_chunk_bytes > ws_size) {
        nch = (int)(ws_size / per_chunk_bytes);
        if (nch < 1) nch = 1;
    }
    int chunk = ((NTRAIN + nch - 1) / nch + (NT - 1)) & ~(NT - 1);  // multiple of 32

    Cand* part = (Cand*)d_ws;   // T * nch * 5 * 8B (default 5.12 MB)

    knn_mfma<<<dim3(T / TB, nch), 256, 0, stream>>>(X, XT, part, nch, chunk);
    knn_vote<<<dim3((T + 255) / 256), 256, 0, stream>>>(part, y, (float*)d_out, nch);
}

// Round 3
// 286.024 us; speedup vs baseline: 2.6777x; 2.0857x over previous
//
#include <hip/hip_runtime.h>
#include <cfloat>
#include <cstdint>

// KNN classify via split-f16 MFMA emulated-fp32 GEMM.
// key = dot(x,t) - ||t||^2/2 ; dot = hiA*hiB + hiA*loB + loA*hiB (f32-accum MFMA).
// -nrm/2 folded in as augmented MFMA with reg-held A fragment.
// Top-5 largest keys, ties -> smaller train index (matches lax.top_k on -dist).

#define NTRAIN 100000
#define D 128
#define T 1024
#define TB 256        // tests per block (4 waves x 64)
#define NT 32         // trains per tile
#define KNN 5
#define NUM_CLASSES 10
#define DEF_NCH 125   // 125 chunks x 800 trains = 100000 exactly

typedef _Float16 half8 __attribute__((ext_vector_type(8)));
typedef float f32x16 __attribute__((ext_vector_type(16)));

#define MFMA(a, b, c) __builtin_amdgcn_mfma_f32_32x32x16_f16((a), (b), (c), 0, 0, 0)

struct Cand { float s; int j; };

__device__ __forceinline__ bool better(float s, int j, const Cand& c) {
    return (s > c.s) || (s == c.s && j < c.j);
}

__device__ __forceinline__ void ins5(Cand t5[KNN], float s, int j) {
    if (!better(s, j, t5[4])) return;
    if (better(s, j, t5[0]))      { t5[4]=t5[3]; t5[3]=t5[2]; t5[2]=t5[1]; t5[1]=t5[0]; t5[0]={s,j}; }
    else if (better(s, j, t5[1])) { t5[4]=t5[3]; t5[3]=t5[2]; t5[2]=t5[1]; t5[1]={s,j}; }
    else if (better(s, j, t5[2])) { t5[4]=t5[3]; t5[3]=t5[2]; t5[2]={s,j}; }
    else if (better(s, j, t5[3])) { t5[4]=t5[3]; t5[3]={s,j}; }
    else                          { t5[4]={s,j}; }
}

__device__ __forceinline__ float max16(const f32x16& a) {
    float m0 = fmaxf(a[0], a[1]),  m1 = fmaxf(a[2], a[3]);
    float m2 = fmaxf(a[4], a[5]),  m3 = fmaxf(a[6], a[7]);
    float m4 = fmaxf(a[8], a[9]),  m5 = fmaxf(a[10], a[11]);
    float m6 = fmaxf(a[12], a[13]), m7 = fmaxf(a[14], a[15]);
    m0 = fmaxf(m0, m1); m2 = fmaxf(m2, m3); m4 = fmaxf(m4, m5); m6 = fmaxf(m6, m7);
    return fmaxf(fmaxf(m0, m2), fmaxf(m4, m6));
}

// ---- norms: binary tree over 32 float4-chunk partials (bit-matches the
// round-2 shfl_xor(1,2,4,8,16) tree that passed validation) ----
__global__ __launch_bounds__(256)
void knn_norms(const float* __restrict__ XT, float* __restrict__ nrm2) {
    const int j = blockIdx.x * 256 + threadIdx.x;
    if (j >= NTRAIN) return;
    const float4* row = (const float4*)&XT[(size_t)j * D];
    float p[32];
#pragma unroll
    for (int c = 0; c < 32; ++c) {
        float4 v = row[c];
        p[c] = v.x * v.x + v.y * v.y + v.z * v.z + v.w * v.w;
    }
#pragma unroll
    for (int s = 1; s < 32; s <<= 1)
#pragma unroll
        for (int i = 0; i < 32; i += 2 * s) p[i] += p[i + s];
    nrm2[j] = p[0];
}

__global__ __launch_bounds__(256, 2)
void knn_mfma(const float* __restrict__ X, const float* __restrict__ XT,
              const float* __restrict__ nrm2, Cand* __restrict__ part,
              int nch, int chunk) {
    // Packed LDS per buffer: Ah units [8 ks][2 khalf][32 row][8 f16] = 16 KB,
    // Al at +8192 halves. MFMA A-frag read = base + ks*1024B + lane*16B:
    // 64 lanes read 1024 consecutive bytes -> conflict-free ds_read_b128.
    __shared__ __align__(16) _Float16 lds[2][16384];   // 64 KB total

    const int tid  = threadIdx.x;
    const int lane = tid & 63;
    const int wm   = tid >> 6;
    const int bx   = blockIdx.x;
    const int bc   = blockIdx.y;

    // ---- persistent B (tests) fragments, hi/lo split ----
    half8 Bh[2][8], Bl[2][8];
#pragma unroll
    for (int c = 0; c < 2; ++c) {
        const int trow = bx * TB + wm * 64 + c * 32 + (lane & 31);
        const float* xp = &X[(size_t)trow * D + (lane >> 5) * 8];
#pragma unroll
        for (int ks = 0; ks < 8; ++ks) {
            float4 v0 = *(const float4*)&xp[ks * 16];
            float4 v1 = *(const float4*)&xp[ks * 16 + 4];
            float a[8] = {v0.x, v0.y, v0.z, v0.w, v1.x, v1.y, v1.z, v1.w};
#pragma unroll
            for (int e = 0; e < 8; ++e) {
                _Float16 hh = (_Float16)a[e];
                Bh[c][ks][e] = hh;
                Bl[c][ks][e] = (_Float16)(a[e] - (float)hh);
            }
        }
    }
    half8 B8;
#pragma unroll
    for (int e = 0; e < 8; ++e) B8[e] = (_Float16)0.0f;
    if (lane < 32) B8[0] = (_Float16)1.0f;

    // ---- staging: thread -> (row = tid&31, ksp = tid>>5), 16 f32 of that row ----
    const int srow = tid & 31;
    const int ksp  = tid >> 5;
    float a16[16];

    auto issue_loads = [&](int jb) {
        int j = jb + srow;
        if (j > NTRAIN - 1) j = NTRAIN - 1;          // clamp (harmless dup data)
        const float4* p = (const float4*)&XT[(size_t)j * D + ksp * 16];
        float4 v0 = p[0], v1 = p[1], v2 = p[2], v3 = p[3];
        a16[0]=v0.x; a16[1]=v0.y; a16[2]=v0.z; a16[3]=v0.w;
        a16[4]=v1.x; a16[5]=v1.y; a16[6]=v1.z; a16[7]=v1.w;
        a16[8]=v2.x; a16[9]=v2.y; a16[10]=v2.z; a16[11]=v2.w;
        a16[12]=v3.x; a16[13]=v3.y; a16[14]=v3.z; a16[15]=v3.w;
    };
    auto write_stage = [&](int buf) {
        half8 hv0, lv0, hv1, lv1;
#pragma unroll
        for (int e = 0; e < 8; ++e) {
            _Float16 hh = (_Float16)a16[e];
            hv0[e] = hh; lv0[e] = (_Float16)(a16[e] - (float)hh);
        }
#pragma unroll
        for (int e = 0; e < 8; ++e) {
            _Float16 hh = (_Float16)a16[8 + e];
            hv1[e] = hh; lv1[e] = (_Float16)(a16[8 + e] - (float)hh);
        }
        _Float16* base = &lds[buf][ksp * 512 + srow * 8];
        *(half8*)(base)              = hv0;   // khalf 0, hi
        *(half8*)(base + 256)        = hv1;   // khalf 1, hi
        *(half8*)(base + 8192)       = lv0;   // khalf 0, lo
        *(half8*)(base + 8192 + 256) = lv1;   // khalf 1, lo
    };

    Cand top[2][KNN];
#pragma unroll
    for (int c = 0; c < 2; ++c)
#pragma unroll
        for (int e = 0; e < KNN; ++e) top[c][e] = {-FLT_MAX, 0x7fffffff};

    const int jc0 = bc * chunk;
    const int ntiles = chunk >> 5;

    issue_loads(jc0);
    write_stage(0);
    __syncthreads();

    for (int t = 0; t < ntiles; ++t) {
        const int jb = jc0 + t * NT;
        if (jb >= NTRAIN) break;                    // uniform
        const int buf = t & 1;
        const bool more = (t + 1 < ntiles);
        if (more) issue_loads(jb + NT);

        // augment source (issued early; consumed after 48 MFMAs)
        int nj = jb + lane;
        if (nj > NTRAIN - 1) nj = NTRAIN - 1;
        const float nr = (lane < 32) ? nrm2[nj] : 0.0f;

        f32x16 accA, accB;
#pragma unroll
        for (int e = 0; e < 16; ++e) { accA[e] = 0.f; accB[e] = 0.f; }

        const _Float16* rbaseh = &lds[buf][lane * 8];
#pragma unroll
        for (int ks = 0; ks < 8; ++ks) {
            half8 ah = *(const half8*)(rbaseh + ks * 512);
            half8 al = *(const half8*)(rbaseh + 8192 + ks * 512);
            accA = MFMA(ah, Bh[0][ks], accA);
            accB = MFMA(ah, Bh[1][ks], accB);
            accA = MFMA(ah, Bl[0][ks], accA);
            accB = MFMA(ah, Bl[1][ks], accB);
            accA = MFMA(al, Bh[0][ks], accA);
            accB = MFMA(al, Bh[1][ks], accB);
        }
        {   // augmented pass: D[row][col] += (-nrm/2)(row)
            half8 augh, augl;
#pragma unroll
            for (int e = 0; e < 8; ++e) { augh[e] = (_Float16)0.0f; augl[e] = (_Float16)0.0f; }
            const float m = -0.5f * nr;
            const _Float16 mh = (_Float16)m;
            if (lane < 32) { augh[0] = mh; augl[0] = (_Float16)(m - (float)mh); }
            accA = MFMA(augh, B8, accA);
            accB = MFMA(augh, B8, accB);
            accA = MFMA(augl, B8, accA);
            accB = MFMA(augl, B8, accB);
        }

        if (more) write_stage(buf ^ 1);

        // ---- epilogue: max-prefilter then insert ----
        const int rb = 4 * (lane >> 5);
        const float mA = max16(accA);
        if (mA > top[0][4].s) {
#pragma unroll
            for (int reg = 0; reg < 16; ++reg) {
                const int j = jb + (reg & 3) + 8 * (reg >> 2) + rb;
                if (j < NTRAIN) ins5(top[0], accA[reg], j);
            }
        }
        const float mB = max16(accB);
        if (mB > top[1][4].s) {
#pragma unroll
            for (int reg = 0; reg < 16; ++reg) {
                const int j = jb + (reg & 3) + 8 * (reg >> 2) + rb;
                if (j < NTRAIN) ins5(top[1], accB[reg], j);
            }
        }
        __syncthreads();
    }

    // ---- merge lane pairs (l <-> l+32), write partials ----
#pragma unroll
    for (int c = 0; c < 2; ++c) {
        float os[KNN]; int oj[KNN];
#pragma unroll
        for (int e = 0; e < KNN; ++e) {
            os[e] = __shfl_xor(top[c][e].s, 32);
            oj[e] = __shfl_xor(top[c][e].j, 32);
        }
#pragma unroll
        for (int e = 0; e < KNN; ++e) ins5(top[c], os[e], oj[e]);
        if (lane < 32) {
            const int test = bx * TB + wm * 64 + c * 32 + lane;
            Cand* pp = &part[((size_t)test * nch + bc) * KNN];
#pragma unroll
            for (int e = 0; e < KNN; ++e) pp[e] = top[c][e];
        }
    }
}

// ---- parallel vote: one wave per test; lanes split chunks, butterfly merge ----
__global__ __launch_bounds__(256)
void knn_vote2(const Cand* __restrict__ part, const int* __restrict__ y,
               float* __restrict__ out, int nch) {
    const int tid  = threadIdx.x;
    const int lane = tid & 63;
    const int test = blockIdx.x * 4 + (tid >> 6);
    if (test >= T) return;

    Cand best[KNN];
#pragma unroll
    for (int e = 0; e < KNN; ++e) best[e] = {-FLT_MAX, 0x7fffffff};

    for (int c = lane; c < nch; c += 64) {
        const Cand* pp = &part[((size_t)test * nch + c) * KNN];
#pragma unroll
        for (int e = 0; e < KNN; ++e) {
            const Cand cc = pp[e];
            if ((unsigned)cc.j < (unsigned)NTRAIN) ins5(best, cc.s, cc.j);
        }
    }
#pragma unroll
    for (int off = 32; off >= 1; off >>= 1) {
        float os[KNN]; int oj[KNN];
#pragma unroll
        for (int e = 0; e < KNN; ++e) {
            os[e] = __shfl_xor(best[e].s, off);
            oj[e] = __shfl_xor(best[e].j, off);
        }
#pragma unroll
        for (int e = 0; e < KNN; ++e)
            if ((unsigned)oj[e] < (unsigned)NTRAIN) ins5(best, os[e], oj[e]);
    }
    if (lane == 0) {
        int lbl[KNN];
#pragma unroll
        for (int e = 0; e < KNN; ++e) lbl[e] = y[best[e].j];
        int bestc = 0, bestcnt = -1;
#pragma unroll
        for (int c = 0; c < NUM_CLASSES; ++c) {
            int cnt = 0;
#pragma unroll
            for (int e = 0; e < KNN; ++e) cnt += (lbl[e] == c) ? 1 : 0;
            if (cnt > bestcnt) { bestcnt = cnt; bestc = c; }
        }
        out[test] = (float)bestc;
    }
}

extern "C" void kernel_launch(void* const* d_in, const int* in_sizes, int n_in,
                              void* d_out, int out_size, void* d_ws, size_t ws_size,
                              hipStream_t stream) {
    const float* X  = (const float*)d_in[0];
    const float* XT = (const float*)d_in[1];
    const int*   y  = (const int*)d_in[2];
    // d_in[3] = k (always 5; hardcoded)

    const size_t nrm_bytes = ((size_t)NTRAIN * 4 + 255) & ~(size_t)255;
    float* nrm2 = (float*)d_ws;
    Cand*  part = (Cand*)((char*)d_ws + nrm_bytes);

    int nch = DEF_NCH;
    const size_t per_chunk_bytes = (size_t)T * KNN * sizeof(Cand);
    if (ws_size > 0 && nrm_bytes + (size_t)nch * per_chunk_bytes > ws_size) {
        size_t avail = (ws_size > nrm_bytes) ? (ws_size - nrm_bytes) : 0;
        nch = (int)(avail / per_chunk_bytes);
        if (nch < 1) nch = 1;
    }
    int chunk = (((NTRAIN + nch - 1) / nch) + (NT - 1)) & ~(NT - 1);

    knn_norms<<<(NTRAIN + 255) / 256, 256, 0, stream>>>(XT, nrm2);
    knn_mfma<<<dim3(T / TB, nch), 256, 0, stream>>>(X, XT, nrm2, part, nch, chunk);
    knn_vote2<<<T / 4, 256, 0, stream>>>(part, y, (float*)d_out, nch);
}

// Round 4
// 267.881 us; speedup vs baseline: 2.8591x; 1.0677x over previous
//
#include <hip/hip_runtime.h>
#include <cfloat>
#include <cstdint>

// KNN classify via split-f16 MFMA emulated-fp32 GEMM.
// key = dot(x,t) - ||t||^2/2 ; dot = hiA*hiB + hiA*loB + loA*hiB (f32-accum MFMA).
// X_train pre-split into tile-packed f16 hi/lo (prep kernel) -> hot loop stages
// via global_load_lds (no VALU). Norm term folded via 2 augment MFMAs per acc
// (bit-identical to validated round-3 sequence).

#define NTRAIN 100000
#define D 128
#define T 1024
#define TB 256          // tests per block (4 waves x 64)
#define NT 32           // trains per tile
#define KNN 5
#define NUM_CLASSES 10
#define NCH 125         // 125 chunks x 800 trains = 100000 exactly
#define CHUNK 800
#define NTILE_TOT 3125  // NTRAIN / NT
#define TILE_HALVES 8192   // per packed tile: hi 4096 + lo 4096 halves (16KB)

typedef _Float16 half8 __attribute__((ext_vector_type(8)));
typedef float f32x16 __attribute__((ext_vector_type(16)));

#define MFMA(a, b, c) __builtin_amdgcn_mfma_f32_32x32x16_f16((a), (b), (c), 0, 0, 0)

struct Cand { float s; int j; };

__device__ __forceinline__ bool better(float s, int j, const Cand& c) {
    return (s > c.s) || (s == c.s && j < c.j);
}

__device__ __forceinline__ void ins5(Cand t5[KNN], float s, int j) {
    if (!better(s, j, t5[4])) return;
    if (better(s, j, t5[0]))      { t5[4]=t5[3]; t5[3]=t5[2]; t5[2]=t5[1]; t5[1]=t5[0]; t5[0]={s,j}; }
    else if (better(s, j, t5[1])) { t5[4]=t5[3]; t5[3]=t5[2]; t5[2]=t5[1]; t5[1]={s,j}; }
    else if (better(s, j, t5[2])) { t5[4]=t5[3]; t5[3]=t5[2]; t5[2]={s,j}; }
    else if (better(s, j, t5[3])) { t5[4]=t5[3]; t5[3]={s,j}; }
    else                          { t5[4]={s,j}; }
}

__device__ __forceinline__ float max16(const f32x16& a) {
    float m0 = fmaxf(a[0], a[1]),  m1 = fmaxf(a[2], a[3]);
    float m2 = fmaxf(a[4], a[5]),  m3 = fmaxf(a[6], a[7]);
    float m4 = fmaxf(a[8], a[9]),  m5 = fmaxf(a[10], a[11]);
    float m6 = fmaxf(a[12], a[13]), m7 = fmaxf(a[14], a[15]);
    m0 = fmaxf(m0, m1); m2 = fmaxf(m2, m3); m4 = fmaxf(m4, m5); m6 = fmaxf(m6, m7);
    return fmaxf(fmaxf(m0, m2), fmaxf(m4, m6));
}

__device__ __forceinline__ void gload_lds16(const void* g, void* l) {
    __builtin_amdgcn_global_load_lds(
        (const __attribute__((address_space(1))) uint32_t*)g,
        (__attribute__((address_space(3))) uint32_t*)l, 16, 0, 0);
}

// ---- norms -> packed (mh, ml) of m = -0.5*||t||^2 (tree bit-matches r2/r3) ----
__global__ __launch_bounds__(256)
void knn_norms(const float* __restrict__ XT, uint32_t* __restrict__ nrmp) {
    const int j = blockIdx.x * 256 + threadIdx.x;
    if (j >= NTRAIN) return;
    const float4* row = (const float4*)&XT[(size_t)j * D];
    float p[32];
#pragma unroll
    for (int c = 0; c < 32; ++c) {
        float4 v = row[c];
        p[c] = v.x * v.x + v.y * v.y + v.z * v.z + v.w * v.w;
    }
#pragma unroll
    for (int s = 1; s < 32; s <<= 1)
#pragma unroll
        for (int i = 0; i < 32; i += 2 * s) p[i] += p[i + s];
    const float m = -0.5f * p[0];
    const _Float16 mh = (_Float16)m;
    const _Float16 ml = (_Float16)(m - (float)mh);
    union { _Float16 h[2]; uint32_t u; } cv;
    cv.h[0] = mh; cv.h[1] = ml;
    nrmp[j] = cv.u;
}

// ---- pre-split XT into tile-packed hi/lo f16 (MFMA A-fragment order) ----
// tile block (16KB): hi o = ks*512 + khalf*256 + row*8 + e  (k = ks*16+khalf*8+e),
// lo at +4096. Conversion ops bit-identical to r3 write_stage.
__global__ __launch_bounds__(256)
void knn_pack(const float* __restrict__ XT, _Float16* __restrict__ XTs) {
    __shared__ __align__(16) float sb[32 * D];
    const int tid  = threadIdx.x;
    const int tile = blockIdx.x;
    const float4* src = (const float4*)&XT[(size_t)tile * 32 * D];
#pragma unroll
    for (int p = 0; p < 4; ++p)
        *(float4*)&sb[(p * 256 + tid) * 4] = src[p * 256 + tid];
    __syncthreads();
    const int ks = tid >> 5, kh = (tid >> 4) & 1, rp = (tid & 15) * 2;
    const int c0 = ks * 16 + kh * 8;
    _Float16* out = &XTs[(size_t)tile * TILE_HALVES + tid * 16];
#pragma unroll
    for (int rr = 0; rr < 2; ++rr) {
        const float* s = &sb[(rp + rr) * D + c0];
        half8 hv, lv;
#pragma unroll
        for (int e = 0; e < 8; ++e) {
            float v = s[e];
            _Float16 hh = (_Float16)v;
            hv[e] = hh; lv[e] = (_Float16)(v - (float)hh);
        }
        *(half8*)&out[rr * 8]        = hv;
        *(half8*)&out[4096 + rr * 8] = lv;
    }
}

template <bool SPLIT>
__global__ __launch_bounds__(256, 2)
void knn_mfma(const float* __restrict__ X, const float* __restrict__ XT,
              const _Float16* __restrict__ XTs, const uint32_t* __restrict__ nrmp,
              Cand* __restrict__ part, int nch, int chunk) {
    __shared__ __align__(16) _Float16 lds[2][TILE_HALVES];   // 32 KB

    const int tid  = threadIdx.x;
    const int lane = tid & 63;
    const int wv   = tid >> 6;
    const int bx   = blockIdx.x;
    const int bc   = blockIdx.y;

    // ---- persistent B (tests) fragments, hi/lo split ----
    half8 Bh[2][8], Bl[2][8];
#pragma unroll
    for (int c = 0; c < 2; ++c) {
        const int trow = bx * TB + wv * 64 + c * 32 + (lane & 31);
        const float* xp = &X[(size_t)trow * D + (lane >> 5) * 8];
#pragma unroll
        for (int ks = 0; ks < 8; ++ks) {
            float4 v0 = *(const float4*)&xp[ks * 16];
            float4 v1 = *(const float4*)&xp[ks * 16 + 4];
            float a[8] = {v0.x, v0.y, v0.z, v0.w, v1.x, v1.y, v1.z, v1.w};
#pragma unroll
            for (int e = 0; e < 8; ++e) {
                _Float16 hh = (_Float16)a[e];
                Bh[c][ks][e] = hh;
                Bl[c][ks][e] = (_Float16)(a[e] - (float)hh);
            }
        }
    }
    half8 B8;
#pragma unroll
    for (int e = 0; e < 8; ++e) B8[e] = (_Float16)0.0f;
    if (lane < 32) B8[0] = (_Float16)1.0f;

    // ---- staging (SPLIT: 4x global_load_lds 16B; fallback: reg-staged cvt) ----
    const int srow = tid & 31;
    const int ksp  = tid >> 5;
    float a16[16];

    auto issue_stage_split = [&](int buf, int tile) {
        const _Float16* g = &XTs[(size_t)tile * TILE_HALVES + wv * 512 + lane * 8];
        _Float16* l = &lds[buf][wv * 512];
#pragma unroll
        for (int p = 0; p < 4; ++p)
            gload_lds16(g + p * 2048, l + p * 2048);
    };
    auto issue_loads = [&](int jb) {
        int j = jb + srow;
        if (j > NTRAIN - 1) j = NTRAIN - 1;
        const float4* p = (const float4*)&XT[(size_t)j * D + ksp * 16];
        float4 v0 = p[0], v1 = p[1], v2 = p[2], v3 = p[3];
        a16[0]=v0.x; a16[1]=v0.y; a16[2]=v0.z; a16[3]=v0.w;
        a16[4]=v1.x; a16[5]=v1.y; a16[6]=v1.z; a16[7]=v1.w;
        a16[8]=v2.x; a16[9]=v2.y; a16[10]=v2.z; a16[11]=v2.w;
        a16[12]=v3.x; a16[13]=v3.y; a16[14]=v3.z; a16[15]=v3.w;
    };
    auto write_stage = [&](int buf) {
        half8 hv0, lv0, hv1, lv1;
#pragma unroll
        for (int e = 0; e < 8; ++e) {
            _Float16 hh = (_Float16)a16[e];
            hv0[e] = hh; lv0[e] = (_Float16)(a16[e] - (float)hh);
        }
#pragma unroll
        for (int e = 0; e < 8; ++e) {
            _Float16 hh = (_Float16)a16[8 + e];
            hv1[e] = hh; lv1[e] = (_Float16)(a16[8 + e] - (float)hh);
        }
        _Float16* base = &lds[buf][ksp * 512 + srow * 8];
        *(half8*)(base)              = hv0;
        *(half8*)(base + 256)        = hv1;
        *(half8*)(base + 4096)       = lv0;
        *(half8*)(base + 4096 + 256) = lv1;
    };

    Cand top[2][KNN];
#pragma unroll
    for (int c = 0; c < 2; ++c)
#pragma unroll
        for (int e = 0; e < KNN; ++e) top[c][e] = {-FLT_MAX, 0x7fffffff};

    const int jc0 = bc * chunk;
    const int ntiles = chunk >> 5;
    const int tile0 = jc0 >> 5;

    if (SPLIT) {
        issue_stage_split(0, tile0);
    } else {
        issue_loads(jc0);
        write_stage(0);
    }
    __syncthreads();

    for (int t = 0; t < ntiles; ++t) {
        const int jb = jc0 + t * NT;
        if (!SPLIT && jb >= NTRAIN) break;           // uniform (fallback only)
        const int buf = t & 1;
        const bool more = (t + 1 < ntiles);

        if (SPLIT) {
            if (more) issue_stage_split(buf ^ 1, tile0 + t + 1);
        } else {
            if (more) issue_loads(jb + NT);
        }

        // augment source: packed (mh, ml) of -0.5*||t||^2
        uint32_t nv = 0;
        if (lane < 32) {
            int nj = jb + lane;
            if (!SPLIT && nj > NTRAIN - 1) nj = NTRAIN - 1;
            nv = nrmp[nj];
        }

        f32x16 accA, accB;
#pragma unroll
        for (int e = 0; e < 16; ++e) { accA[e] = 0.f; accB[e] = 0.f; }

        const _Float16* rbase = &lds[buf][lane * 8];
#pragma unroll
        for (int ks = 0; ks < 8; ++ks) {
            half8 ah = *(const half8*)(rbase + ks * 512);
            half8 al = *(const half8*)(rbase + 4096 + ks * 512);
            accA = MFMA(ah, Bh[0][ks], accA);
            accB = MFMA(ah, Bh[1][ks], accB);
            accA = MFMA(ah, Bl[0][ks], accA);
            accB = MFMA(ah, Bl[1][ks], accB);
            accA = MFMA(al, Bh[0][ks], accA);
            accB = MFMA(al, Bh[1][ks], accB);
        }
        {   // augmented passes (bit-identical to r3: +mh then +ml)
            union { uint32_t u; _Float16 h[2]; } cv; cv.u = nv;
            half8 augh, augl;
#pragma unroll
            for (int e = 0; e < 8; ++e) { augh[e] = (_Float16)0.0f; augl[e] = (_Float16)0.0f; }
            augh[0] = cv.h[0];
            augl[0] = cv.h[1];
            accA = MFMA(augh, B8, accA);
            accB = MFMA(augh, B8, accB);
            accA = MFMA(augl, B8, accA);
            accB = MFMA(augl, B8, accB);
        }

        if (!SPLIT && more) write_stage(buf ^ 1);

        // ---- epilogue: max-prefilter then insert ----
        const int rb = 4 * (lane >> 5);
        const float mA = max16(accA);
        if (mA > top[0][4].s) {
#pragma unroll
            for (int reg = 0; reg < 16; ++reg) {
                const int j = jb + (reg & 3) + 8 * (reg >> 2) + rb;
                if (SPLIT || j < NTRAIN) ins5(top[0], accA[reg], j);
            }
        }
        const float mB = max16(accB);
        if (mB > top[1][4].s) {
#pragma unroll
            for (int reg = 0; reg < 16; ++reg) {
                const int j = jb + (reg & 3) + 8 * (reg >> 2) + rb;
                if (SPLIT || j < NTRAIN) ins5(top[1], accB[reg], j);
            }
        }
        __syncthreads();
    }

    // ---- merge lane pairs (l <-> l+32), write partials ----
#pragma unroll
    for (int c = 0; c < 2; ++c) {
        float os[KNN]; int oj[KNN];
#pragma unroll
        for (int e = 0; e < KNN; ++e) {
            os[e] = __shfl_xor(top[c][e].s, 32);
            oj[e] = __shfl_xor(top[c][e].j, 32);
        }
#pragma unroll
        for (int e = 0; e < KNN; ++e) ins5(top[c], os[e], oj[e]);
        if (lane < 32) {
            const int test = bx * TB + wv * 64 + c * 32 + lane;
            Cand* pp = &part[((size_t)test * nch + bc) * KNN];
#pragma unroll
            for (int e = 0; e < KNN; ++e) pp[e] = top[c][e];
        }
    }
}

// ---- parallel vote: one wave per test; lanes split chunks, butterfly merge ----
__global__ __launch_bounds__(256)
void knn_vote2(const Cand* __restrict__ part, const int* __restrict__ y,
               float* __restrict__ out, int nch) {
    const int tid  = threadIdx.x;
    const int lane = tid & 63;
    const int test = blockIdx.x * 4 + (tid >> 6);
    if (test >= T) return;

    Cand best[KNN];
#pragma unroll
    for (int e = 0; e < KNN; ++e) best[e] = {-FLT_MAX, 0x7fffffff};

    for (int c = lane; c < nch; c += 64) {
        const Cand* pp = &part[((size_t)test * nch + c) * KNN];
#pragma unroll
        for (int e = 0; e < KNN; ++e) {
            const Cand cc = pp[e];
            if ((unsigned)cc.j < (unsigned)NTRAIN) ins5(best, cc.s, cc.j);
        }
    }
#pragma unroll
    for (int off = 32; off >= 1; off >>= 1) {
        float os[KNN]; int oj[KNN];
#pragma unroll
        for (int e = 0; e < KNN; ++e) {
            os[e] = __shfl_xor(best[e].s, off);
            oj[e] = __shfl_xor(best[e].j, off);
        }
#pragma unroll
        for (int e = 0; e < KNN; ++e)
            if ((unsigned)oj[e] < (unsigned)NTRAIN) ins5(best, os[e], oj[e]);
    }
    if (lane == 0) {
        int lbl[KNN];
#pragma unroll
        for (int e = 0; e < KNN; ++e) lbl[e] = y[best[e].j];
        int bestc = 0, bestcnt = -1;
#pragma unroll
        for (int c = 0; c < NUM_CLASSES; ++c) {
            int cnt = 0;
#pragma unroll
            for (int e = 0; e < KNN; ++e) cnt += (lbl[e] == c) ? 1 : 0;
            if (cnt > bestcnt) { bestcnt = cnt; bestc = c; }
        }
        out[test] = (float)bestc;
    }
}

extern "C" void kernel_launch(void* const* d_in, const int* in_sizes, int n_in,
                              void* d_out, int out_size, void* d_ws, size_t ws_size,
                              hipStream_t stream) {
    const float* X  = (const float*)d_in[0];
    const float* XT = (const float*)d_in[1];
    const int*   y  = (const int*)d_in[2];
    // d_in[3] = k (always 5; hardcoded)

    const size_t xts_bytes  = (size_t)NTILE_TOT * TILE_HALVES * 2;      // 51.2 MB
    const size_t nrm_bytes  = ((size_t)NTRAIN * 4 + 255) & ~(size_t)255;
    const size_t part_bytes = (size_t)T * NCH * KNN * sizeof(Cand);     // 5.12 MB

    if (ws_size >= xts_bytes + nrm_bytes + part_bytes) {
        _Float16* XTs  = (_Float16*)d_ws;
        uint32_t* nrmp = (uint32_t*)((char*)d_ws + xts_bytes);
        Cand*     part = (Cand*)((char*)d_ws + xts_bytes + nrm_bytes);
        knn_norms<<<(NTRAIN + 255) / 256, 256, 0, stream>>>(XT, nrmp);
        knn_pack<<<NTILE_TOT, 256, 0, stream>>>(XT, XTs);
        knn_mfma<true><<<dim3(T / TB, NCH), 256, 0, stream>>>(X, XT, XTs, nrmp, part, NCH, CHUNK);
        knn_vote2<<<T / 4, 256, 0, stream>>>(part, y, (float*)d_out, NCH);
    } else {
        // fallback: in-loop conversion (round-3 structure), smaller ws footprint
        uint32_t* nrmp = (uint32_t*)d_ws;
        Cand*     part = (Cand*)((char*)d_ws + nrm_bytes);
        int nch = NCH;
        if (nrm_bytes + (size_t)nch * T * KNN * sizeof(Cand) > ws_size) {
            size_t avail = (ws_size > nrm_bytes) ? (ws_size - nrm_bytes) : 0;
            nch = (int)(avail / ((size_t)T * KNN * sizeof(Cand)));
            if (nch < 1) nch = 1;
        }
        int chunk = (((NTRAIN + nch - 1) / nch) + (NT - 1)) & ~(NT - 1);
        knn_norms<<<(NTRAIN + 255) / 256, 256, 0, stream>>>(XT, nrmp);
        knn_mfma<false><<<dim3(T / TB, nch), 256, 0, stream>>>(X, XT, nullptr, nrmp, part, nch, chunk);
        knn_vote2<<<T / 4, 256, 0, stream>>>(part, y, (float*)d_out, nch);
    }
}